// Round 11
// baseline (136.906 us; speedup 1.0000x reference)
//
#include <hip/hip_runtime.h>
#include <math.h>

#define NN 1024
#define DD 64
#define HH 256
#define TEMP_INV 10.0f
#define KCH 64
#define NCH 4

typedef float v2f __attribute__((ext_vector_type(2)));

// ws layout (floats):
//   x2T [HH][NN] : xp + b1, k-major     1 MB
//   y2  [NN][HH] : yp, row-major        1 MB
//   pmax [16][NN], psum [16][NN], pos [NN]

__global__ __launch_bounds__(256)
void k1_proj(const float* __restrict__ x, const float* __restrict__ y,
             const float* __restrict__ W1, const float* __restrict__ b1,
             float* __restrict__ x2T, float* __restrict__ y2)
{
    const int tid = threadIdx.x;        // h index 0..255
    const int i0 = blockIdx.x * 2;      // 2 rows per block -> 512 blocks
    float ax0 = 0.f, ax1 = 0.f, ay0 = 0.f, ay1 = 0.f;
    #pragma unroll 8
    for (int kk = 0; kk < DD; ++kk) {
        const float wx = W1[kk * HH + tid];
        const float wy = W1[(DD + kk) * HH + tid];
        ax0 = fmaf(x[i0 * DD + kk],       wx, ax0);
        ax1 = fmaf(x[(i0 + 1) * DD + kk], wx, ax1);
        ay0 = fmaf(y[i0 * DD + kk],       wy, ay0);
        ay1 = fmaf(y[(i0 + 1) * DD + kk], wy, ay1);
    }
    const float b1t = b1[tid];
    *(float2*)&x2T[tid * NN + i0] = make_float2(ax0 + b1t, ax1 + b1t);
    y2[i0 * HH + tid]       = ay0;      // coalesced over tid
    y2[(i0 + 1) * HH + tid] = ay1;
}

// 32 rows x 64 cols per block, full K=256. 512 blocks x 256 thr = 2 blocks/CU
// = 2 waves/SIMD. Per thread: 4 rows (y in regs, prefetched) x 2 packed cols
// (x via LDS ds_read_b64, staged issue-early/write-late). One LDS read per kk.
__global__ __launch_bounds__(256, 2)
void k2_scores(const float* __restrict__ x2T, const float* __restrict__ y2,
               const float* __restrict__ w2, const float* __restrict__ b2,
               float* __restrict__ pmax, float* __restrict__ psum,
               float* __restrict__ pos)
{
    __shared__ float xs[KCH][64];      // 16 KB
    const int t  = threadIdx.x;
    const int bj = blockIdx.x;         // 0..15 -> 64 cols
    const int bi = blockIdx.y;         // 0..31 -> 32 rows
    const int j0 = bj * 64;
    const int rr = t >> 5;             // 0..7
    const int cc = t & 31;             // 0..31
    const int rbase = bi * 32 + rr * 4;
    const float* yb = y2 + rbase * HH;

    // stage-element coords: each thread stages 4 rows: sr, sr+16, sr+32, sr+48
    const int sr  = t >> 4;            // 0..15
    const int sc4 = (t & 15) * 4;

    v2f acc[4];
    #pragma unroll
    for (int p = 0; p < 4; ++p) acc[p] = (v2f){0.f, 0.f};
    const v2f zero = {0.f, 0.f};

    float4 sv[4];                      // staged x chunk (issue-early)
    #pragma unroll
    for (int h = 0; h < 4; ++h)
        sv[h] = *(const float4*)&x2T[(h * 16 + sr) * NN + j0 + sc4];

    float4 yC[4], yN[4];
    #pragma unroll
    for (int p = 0; p < 4; ++p) yC[p] = *(const float4*)&yb[p * HH];

    for (int c = 0; c < NCH; ++c) {
        __syncthreads();               // previous chunk's readers done
        #pragma unroll
        for (int h = 0; h < 4; ++h)
            *(float4*)&xs[h * 16 + sr][sc4] = sv[h];
        __syncthreads();
        if (c + 1 < NCH) {             // issue next chunk's loads now,
            const int kn = (c + 1) * KCH;  // consumed after next barrier
            #pragma unroll
            for (int h = 0; h < 4; ++h)
                sv[h] = *(const float4*)&x2T[(kn + h * 16 + sr) * NN + j0 + sc4];
        }
        #pragma unroll
        for (int g = 0; g < 16; ++g) {
            const int gg = c * 16 + g;
            if (gg + 1 < 64) {         // prefetch next y group (4 kk)
                #pragma unroll
                for (int p = 0; p < 4; ++p)
                    yN[p] = *(const float4*)&yb[p * HH + (gg + 1) * 4];
            }
            #pragma unroll
            for (int e = 0; e < 4; ++e) {
                const int k  = gg * 4 + e;     // global k (uniform)
                const int kl = g * 4 + e;      // row within chunk
                const float wk = w2[k];        // uniform -> s_load
                const v2f wv = {wk, wk};
                const v2f xv = *(const v2f*)&xs[kl][cc * 2];
                #pragma unroll
                for (int p = 0; p < 4; ++p) {
                    const float yv = (e == 0) ? yC[p].x : (e == 1) ? yC[p].y
                                   : (e == 2) ? yC[p].z : yC[p].w;
                    v2f z = xv + (v2f){yv, yv};             // v_pk_add_f32
                    z = __builtin_elementwise_max(z, zero); // v_pk_max_f32
                    acc[p] = z * wv + acc[p];               // v_pk_fma_f32
                }
            }
            #pragma unroll
            for (int p = 0; p < 4; ++p) yC[p] = yN[p];
        }
    }

    // epilogue: scores, diagonal -> pos, per-row partial LSE over 64 cols
    const float bb = b2[0];
    const v2f bbv = {bb, bb};
    v2f sc[4];
    #pragma unroll
    for (int p = 0; p < 4; ++p) sc[p] = (acc[p] + bbv) * TEMP_INV;

    const int col0 = j0 + cc * 2;
    #pragma unroll
    for (int p = 0; p < 4; ++p) {
        const int row = rbase + p;
        if (row == col0)     pos[row] = sc[p].x;
        if (row == col0 + 1) pos[row] = sc[p].y;
    }

    float m[4], e[4];
    #pragma unroll
    for (int p = 0; p < 4; ++p) {
        m[p] = fmaxf(sc[p].x, sc[p].y);
        e[p] = __expf(sc[p].x - m[p]) + __expf(sc[p].y - m[p]);
    }
    #pragma unroll
    for (int mk = 16; mk >= 1; mk >>= 1) {   // reduce over cc (stays in half-wave)
        #pragma unroll
        for (int p = 0; p < 4; ++p) {
            const float mo = __shfl_xor(m[p], mk);
            const float eo = __shfl_xor(e[p], mk);
            const float mn = fmaxf(m[p], mo);
            e[p] = e[p] * __expf(m[p] - mn) + eo * __expf(mo - mn);
            m[p] = mn;
        }
    }
    if (cc == 0) {
        #pragma unroll
        for (int p = 0; p < 4; ++p) {
            pmax[bj * NN + rbase + p] = m[p];
            psum[bj * NN + rbase + p] = e[p];
        }
    }
}

// Single block, 1024 threads: one row per thread. Merge 16 j-chunk partials,
// add pos, block-reduce, write the scalar.
__global__ __launch_bounds__(1024)
void k3_final(const float* __restrict__ pmax, const float* __restrict__ psum,
              const float* __restrict__ pos, float* __restrict__ out)
{
    __shared__ float2 red[1024];
    const int tid = threadIdx.x;      // row
    float M = pmax[tid], E = psum[tid];
    #pragma unroll
    for (int jc = 1; jc < 16; ++jc) {
        const float Mo = pmax[jc * NN + tid];
        const float Eo = psum[jc * NN + tid];
        const float Mn = fmaxf(M, Mo);
        E = E * __expf(M - Mn) + Eo * __expf(Mo - Mn);
        M = Mn;
    }
    red[tid] = make_float2(M + logf(E), pos[tid]);
    __syncthreads();
    for (int s = 512; s > 0; s >>= 1) {
        if (tid < s) {
            const float2 o = red[tid + s];
            float2 m2 = red[tid];
            m2.x += o.x; m2.y += o.y;
            red[tid] = m2;
        }
        __syncthreads();
    }
    if (tid == 0)
        out[0] = red[0].x / (float)NN - logf((float)NN) - red[0].y / (float)NN;
}

extern "C" void kernel_launch(void* const* d_in, const int* in_sizes, int n_in,
                              void* d_out, int out_size, void* d_ws, size_t ws_size,
                              hipStream_t stream)
{
    const float* x  = (const float*)d_in[0];
    const float* y  = (const float*)d_in[1];
    const float* W1 = (const float*)d_in[2];
    const float* b1 = (const float*)d_in[3];
    const float* w2 = (const float*)d_in[4];
    const float* b2 = (const float*)d_in[5];
    float* out = (float*)d_out;

    float* ws   = (float*)d_ws;
    float* x2T  = ws;                 // 256*1024
    float* y2   = x2T + HH * NN;      // 1024*256
    float* pmax = y2 + NN * HH;       // 16*1024
    float* psum = pmax + 16 * NN;     // 16*1024
    float* pos  = psum + 16 * NN;     // 1024

    hipLaunchKernelGGL(k1_proj, dim3(NN / 2), dim3(256), 0, stream,
                       x, y, W1, b1, x2T, y2);
    hipLaunchKernelGGL(k2_scores, dim3(16, 32), dim3(256), 0, stream,
                       x2T, y2, w2, b2, pmax, psum, pos);
    hipLaunchKernelGGL(k3_final, dim3(1), dim3(1024), 0, stream,
                       pmax, psum, pos, out);
}

// Round 12
// 40.744 us; speedup vs baseline: 3.3602x; 3.3602x over previous
//
#include <hip/hip_runtime.h>
#include <math.h>

#define NN 1024
#define DD 64
#define HH 256
#define TEMP_INV 10.0f
#define KCH 64
#define NCH 4

typedef float v2f __attribute__((ext_vector_type(2)));

// ws layout (floats):
//   x2T [HH][NN] : xp + b1, k-major     1 MB
//   y2  [NN][HH] : yp, row-major        1 MB
//   pmax [16][NN], psum [16][NN], pos [NN]

__global__ __launch_bounds__(256)
void k1_proj(const float* __restrict__ x, const float* __restrict__ y,
             const float* __restrict__ W1, const float* __restrict__ b1,
             float* __restrict__ x2T, float* __restrict__ y2)
{
    const int tid = threadIdx.x;        // h index 0..255
    const int i0 = blockIdx.x * 2;      // 2 rows per block -> 512 blocks
    float ax0 = 0.f, ax1 = 0.f, ay0 = 0.f, ay1 = 0.f;
    #pragma unroll 8
    for (int kk = 0; kk < DD; ++kk) {
        const float wx = W1[kk * HH + tid];
        const float wy = W1[(DD + kk) * HH + tid];
        ax0 = fmaf(x[i0 * DD + kk],       wx, ax0);
        ax1 = fmaf(x[(i0 + 1) * DD + kk], wx, ax1);
        ay0 = fmaf(y[i0 * DD + kk],       wy, ay0);
        ay1 = fmaf(y[(i0 + 1) * DD + kk], wy, ay1);
    }
    const float b1t = b1[tid];
    *(float2*)&x2T[tid * NN + i0] = make_float2(ax0 + b1t, ax1 + b1t);
    y2[i0 * HH + tid]       = ay0;      // coalesced over tid
    y2[(i0 + 1) * HH + tid] = ay1;
}

// 32 rows x 64 cols per block, full K=256. 512 blocks x 256 thr = 2 blocks/CU
// = 2 waves/SIMD. x staged via global_load_lds (no VGPR round-trip) into a
// double-buffered LDS tile; y loaded as float4 from L2 inside the unrolled
// loop (compiler-scheduled). Inner: 1 ds_read_b64 + 12 packed VALU per kk.
__global__ __launch_bounds__(256, 2)
void k2_scores(const float* __restrict__ x2T, const float* __restrict__ y2,
               const float* __restrict__ w2, const float* __restrict__ b2,
               float* __restrict__ pmax, float* __restrict__ psum,
               float* __restrict__ pos)
{
    __shared__ float xs[2][KCH][64];   // 32 KB, double-buffered
    const int t  = threadIdx.x;
    const int bj = blockIdx.x;         // 0..15 -> 64 cols
    const int bi = blockIdx.y;         // 0..31 -> 32 rows
    const int j0 = bj * 64;
    const int rr = t >> 5;             // 0..7
    const int cc = t & 31;             // 0..31
    const int rbase = bi * 32 + rr * 4;
    const float* yb = y2 + rbase * HH;

    const int wv  = t >> 6;            // wave id 0..3 (wave-uniform)
    const int ln  = t & 63;
    const int sro = ln >> 4;           // 0..3 (row within 4-row group)
    const int sco = (ln & 15) * 4;     // col within row

    v2f acc[4];
    #pragma unroll
    for (int p = 0; p < 4; ++p) acc[p] = (v2f){0.f, 0.f};
    const v2f zero = {0.f, 0.f};

    // Stage chunk c into buffer b: each wave fills 16 rows via 4 async
    // global_load_lds (dest = wave-uniform base + lane*16, linear).
    #define STAGE(c, b)                                                        \
    {                                                                          \
        _Pragma("unroll")                                                      \
        for (int h = 0; h < 4; ++h) {                                          \
            const int row = wv * 16 + h * 4;                                   \
            const float* gsrc =                                               \
                &x2T[((c) * KCH + row + sro) * NN + j0 + sco];                 \
            __builtin_amdgcn_global_load_lds(                                  \
                (const __attribute__((address_space(1))) unsigned int*)gsrc,   \
                (__attribute__((address_space(3))) unsigned int*)&xs[b][row][0],\
                16, 0, 0);                                                     \
        }                                                                      \
    }

    STAGE(0, 0);
    for (int c = 0; c < NCH; ++c) {
        __syncthreads();               // drains vmcnt -> buf[c&1] ready; also
                                       // guarantees buf^1 readers (chunk c-1) done
        if (c + 1 < NCH) STAGE(c + 1, (c + 1) & 1);   // async into other buffer
        const int cur = c & 1;
        #pragma unroll
        for (int g = 0; g < 16; ++g) {
            const int gg = c * 16 + g;
            float4 yv4[4];
            #pragma unroll
            for (int p = 0; p < 4; ++p)
                yv4[p] = *(const float4*)&yb[p * HH + gg * 4];
            #pragma unroll
            for (int e = 0; e < 4; ++e) {
                const float wk = w2[gg * 4 + e];      // uniform -> s_load
                const v2f wv2 = {wk, wk};
                const v2f xv = *(const v2f*)&xs[cur][g * 4 + e][cc * 2];
                #pragma unroll
                for (int p = 0; p < 4; ++p) {
                    const float yv = (e == 0) ? yv4[p].x : (e == 1) ? yv4[p].y
                                   : (e == 2) ? yv4[p].z : yv4[p].w;
                    v2f z = xv + (v2f){yv, yv};             // v_pk_add_f32
                    z = __builtin_elementwise_max(z, zero); // v_pk_max_f32
                    acc[p] = z * wv2 + acc[p];              // v_pk_fma_f32
                }
            }
        }
    }
    #undef STAGE

    // epilogue: scores, diagonal -> pos, per-row partial LSE over 64 cols
    const float bb = b2[0];
    const v2f bbv = {bb, bb};
    v2f sc[4];
    #pragma unroll
    for (int p = 0; p < 4; ++p) sc[p] = (acc[p] + bbv) * TEMP_INV;

    const int col0 = j0 + cc * 2;
    #pragma unroll
    for (int p = 0; p < 4; ++p) {
        const int row = rbase + p;
        if (row == col0)     pos[row] = sc[p].x;
        if (row == col0 + 1) pos[row] = sc[p].y;
    }

    float m[4], e[4];
    #pragma unroll
    for (int p = 0; p < 4; ++p) {
        m[p] = fmaxf(sc[p].x, sc[p].y);
        e[p] = __expf(sc[p].x - m[p]) + __expf(sc[p].y - m[p]);
    }
    #pragma unroll
    for (int mk = 16; mk >= 1; mk >>= 1) {   // reduce over cc (within 32 lanes)
        #pragma unroll
        for (int p = 0; p < 4; ++p) {
            const float mo = __shfl_xor(m[p], mk);
            const float eo = __shfl_xor(e[p], mk);
            const float mn = fmaxf(m[p], mo);
            e[p] = e[p] * __expf(m[p] - mn) + eo * __expf(mo - mn);
            m[p] = mn;
        }
    }
    if (cc == 0) {
        #pragma unroll
        for (int p = 0; p < 4; ++p) {
            pmax[bj * NN + rbase + p] = m[p];
            psum[bj * NN + rbase + p] = e[p];
        }
    }
}

// Single block, 1024 threads: one row per thread. Merge 16 j-chunk partials,
// add pos, block-reduce, write the scalar.
__global__ __launch_bounds__(1024)
void k3_final(const float* __restrict__ pmax, const float* __restrict__ psum,
              const float* __restrict__ pos, float* __restrict__ out)
{
    __shared__ float2 red[1024];
    const int tid = threadIdx.x;      // row
    float M = pmax[tid], E = psum[tid];
    #pragma unroll
    for (int jc = 1; jc < 16; ++jc) {
        const float Mo = pmax[jc * NN + tid];
        const float Eo = psum[jc * NN + tid];
        const float Mn = fmaxf(M, Mo);
        E = E * __expf(M - Mn) + Eo * __expf(Mo - Mn);
        M = Mn;
    }
    red[tid] = make_float2(M + logf(E), pos[tid]);
    __syncthreads();
    for (int s = 512; s > 0; s >>= 1) {
        if (tid < s) {
            const float2 o = red[tid + s];
            float2 m2 = red[tid];
            m2.x += o.x; m2.y += o.y;
            red[tid] = m2;
        }
        __syncthreads();
    }
    if (tid == 0)
        out[0] = red[0].x / (float)NN - logf((float)NN) - red[0].y / (float)NN;
}

extern "C" void kernel_launch(void* const* d_in, const int* in_sizes, int n_in,
                              void* d_out, int out_size, void* d_ws, size_t ws_size,
                              hipStream_t stream)
{
    const float* x  = (const float*)d_in[0];
    const float* y  = (const float*)d_in[1];
    const float* W1 = (const float*)d_in[2];
    const float* b1 = (const float*)d_in[3];
    const float* w2 = (const float*)d_in[4];
    const float* b2 = (const float*)d_in[5];
    float* out = (float*)d_out;

    float* ws   = (float*)d_ws;
    float* x2T  = ws;                 // 256*1024
    float* y2   = x2T + HH * NN;      // 1024*256
    float* pmax = y2 + NN * HH;       // 16*1024
    float* psum = pmax + 16 * NN;     // 16*1024
    float* pos  = psum + 16 * NN;     // 1024

    hipLaunchKernelGGL(k1_proj, dim3(NN / 2), dim3(256), 0, stream,
                       x, y, W1, b1, x2T, y2);
    hipLaunchKernelGGL(k2_scores, dim3(16, 32), dim3(256), 0, stream,
                       x2T, y2, w2, b2, pmax, psum, pos);
    hipLaunchKernelGGL(k3_final, dim3(1), dim3(1024), 0, stream,
                       pmax, psum, pos, out);
}